// Round 8
// baseline (621.573 us; speedup 1.0000x reference)
//
#include <hip/hip_runtime.h>
#include <hip/hip_bf16.h>
#include <stdint.h>

typedef short short8 __attribute__((ext_vector_type(8)));
typedef float f32x4  __attribute__((ext_vector_type(4)));

typedef __attribute__((address_space(1))) uint32_t u32_g;
typedef __attribute__((address_space(3))) uint32_t u32_l;

#define BM 128
#define BN 128
#define BK 32
// 4-slot LDS ring: slot s at s*16384; A at +0 (8 KiB), B at +8192 (8 KiB).
// 64 KiB total -> 2 blocks/CU (same as r7's dbuf).

// async global->LDS, 16 bytes per lane. LDS dest must be wave-uniform base +
// lane*16 contiguous (generic LDS pointer low 32 bits == LDS offset on amdgcn).
__device__ __forceinline__ void gld_lds16(const void* g, const void* l) {
  __builtin_amdgcn_global_load_lds((u32_g*)(uintptr_t)g, (u32_l*)(uintptr_t)l, 16, 0, 0);
}

// barrier that memory ops cannot cross (raw s_barrier + compiler fence)
#define BARF() do { __builtin_amdgcn_s_barrier(); asm volatile("" ::: "memory"); } while (0)

// ---------------------------------------------------------------------------
// GEMM: C = epilogue(A[M,K](bf16) @ BT[N,K](bf16)^T + bias(fp32))
// 128x128 tile, 4 waves, BK=32, 4-slot LDS ring with counted vmcnt:
//   iter k: vmcnt(8) -> retire tile k (k+1,k+2 stay in flight, ~3-iter lead)
//           s_barrier (all waves waited -> tile k fully visible)
//           stage tile k+3 into slot (k+3)&3   (slot read at iter k-1: free)
//           8x ds_read_b128 + 16 MFMA on slot k&3
// No vmcnt(0) drain in steady state (the r7 limiter).
// FINAL=0: leaky-relu, bf16 -> Cb (stride 2048), j-inner store order
//          (full 128B lines; WRITE ~34 MB not 66).
// FINAL=1: diag-abs + triangle scatter fp32 Cf[(r*64+c)*8192+m], plus
//          zero-store to mirrored lower-triangle slot (replaces memset).
// ---------------------------------------------------------------------------
template <int FINAL>
__global__ __launch_bounds__(256) void gemm_k(
    const __hip_bfloat16* __restrict__ A,
    const __hip_bfloat16* __restrict__ BT,
    const float* __restrict__ bias,
    __hip_bfloat16* __restrict__ Cb,
    float* __restrict__ Cf,
    const int* __restrict__ tbl,
    int K, int Nreal)
{
  __shared__ __attribute__((aligned(16))) char smem[65536];

  const int tid  = threadIdx.x;
  const int lane = tid & 63;
  const int l15  = lane & 15;
  const int quad = lane >> 4;
  const int wave = tid >> 6;
  const int wm   = (wave >> 1) << 6;   // wave row offset within 128-tile
  const int wn   = (wave & 1) << 6;    // wave col offset

  const int bm = blockIdx.x * BM;
  const int bn = blockIdx.y * BN;

  // Row = 32 bf16 = 4 chunks of 16B; chunk c of row r lives at LDS slot
  // (c + (r>>1)) & 3.  Fragment reads (chunk=quad, row=..+l15) then sit at
  // sc = (quad + (l15>>1)) & 3 -- per-thread constant, 2-way bank aliasing
  // (free).  Global source pre-inverse-swizzled so LDS dest stays linear.
  const uint32_t sc16 = (uint32_t)((quad + (l15 >> 1)) & 3) * 16u;

  // Staging: tile = 128 rows x 32 bf16 (64B) per matrix = 2 insts x 256thr x 16B.
  const __hip_bfloat16* ag[2];
  const __hip_bfloat16* bg[2];
  uint32_t lofs[2];
#pragma unroll
  for (int c = 0; c < 2; ++c) {
    int ci  = tid + 256 * c;          // 0..511
    int row = ci >> 2;                // 0..127
    int gch = ((ci & 3) - (ci >> 3)) & 3;   // inverse of (c + (row>>1))&3
    ag[c]   = A  + (size_t)(bm + row) * K + gch * 8;
    bg[c]   = BT + (size_t)(bn + row) * K + gch * 8;
    lofs[c] = (uint32_t)ci * 16u;
  }

  f32x4 acc[4][4];
#pragma unroll
  for (int i = 0; i < 4; ++i)
#pragma unroll
    for (int j = 0; j < 4; ++j)
      acc[i][j] = (f32x4){0.f, 0.f, 0.f, 0.f};

  const int nk = K >> 5;

  // prologue: stage tiles 0,1,2 into slots 0,1,2 (12 loads in flight)
#pragma unroll
  for (int t = 0; t < 3; ++t) {
    char* sb = smem + t * 16384;
#pragma unroll
    for (int c = 0; c < 2; ++c) {
      gld_lds16(ag[c], sb + lofs[c]);
      gld_lds16(bg[c], sb + 8192 + lofs[c]);
      ag[c] += BK;
      bg[c] += BK;
    }
  }

  for (int kt = 0; kt < nk; ++kt) {
    // counted wait: retire exactly tile kt (all waves, before the barrier)
    if (kt < nk - 2)       asm volatile("s_waitcnt vmcnt(8)" ::: "memory");
    else if (kt == nk - 2) asm volatile("s_waitcnt vmcnt(4)" ::: "memory");
    else                   asm volatile("s_waitcnt vmcnt(0)" ::: "memory");
    BARF();

    // stage tile kt+3 -> slot (kt+3)&3 (= slot kt-1, whose reads retired
    // before the previous barrier: all ds_reads are consumed by that iter's
    // MFMAs, so lgkmcnt waited before any wave reached this barrier)
    if (kt + 3 < nk) {
      char* sb = smem + ((kt + 3) & 3) * 16384;
#pragma unroll
      for (int c = 0; c < 2; ++c) {
        gld_lds16(ag[c], sb + lofs[c]);
        gld_lds16(bg[c], sb + 8192 + lofs[c]);
        ag[c] += BK;
        bg[c] += BK;
      }
    }

    const char* rb = smem + (kt & 3) * 16384;
    short8 af[4], bf[4];
#pragma unroll
    for (int i = 0; i < 4; ++i)
      af[i] = *(const short8*)(rb + (wm + i * 16 + l15) * 64 + sc16);
#pragma unroll
    for (int j = 0; j < 4; ++j)
      bf[j] = *(const short8*)(rb + 8192 + (wn + j * 16 + l15) * 64 + sc16);
#pragma unroll
    for (int i = 0; i < 4; ++i)
#pragma unroll
      for (int j = 0; j < 4; ++j)
        acc[i][j] = __builtin_amdgcn_mfma_f32_16x16x32_bf16(af[i], bf[j], acc[i][j], 0, 0, 0);
  }

  // Epilogue. C/D layout: col = lane&15, row = quad*4 + reg (m89-verified).
  if (FINAL == 0) {
    float bv[4];
#pragma unroll
    for (int j = 0; j < 4; ++j) bv[j] = bias[bn + wn + j * 16 + l15];
#pragma unroll
    for (int i = 0; i < 4; ++i) {
#pragma unroll
      for (int r = 0; r < 4; ++r) {
        const size_t rowoff = (size_t)(bm + wm + i * 16 + quad * 4 + r) * 2048;
#pragma unroll
        for (int j = 0; j < 4; ++j) {   // 4 consecutive 32B bursts -> full 128B line
          int n = bn + wn + j * 16 + l15;
          float v = acc[i][j][r] + bv[j];
          v = (v > 0.f) ? v : 0.01f * v;
          Cb[rowoff + n] = __float2bfloat16(v);
        }
      }
    }
  } else {
#pragma unroll
    for (int j = 0; j < 4; ++j) {
      int n = bn + wn + j * 16 + l15;
      if (n < Nreal) {
        float bv   = bias[n];
        int  code  = tbl[n];
        int  dst   = code & 4095;          // r*64 + c (upper triangle)
        bool diag  = (code & 4096) != 0;
        int  mir   = ((dst & 63) << 6) | (dst >> 6);  // (c,r) lower mirror
        const f32x4 z = (f32x4){0.f, 0.f, 0.f, 0.f};
#pragma unroll
        for (int i = 0; i < 4; ++i) {
          int m0 = bm + wm + i * 16 + quad * 4;
          f32x4 pk;
#pragma unroll
          for (int r = 0; r < 4; ++r) {
            float v = acc[i][j][r] + bv;
            if (diag) v = fabsf(v);
            pk[r] = v;
          }
          // 4 consecutive batch rows at one (r,c): aligned 16B store
          *reinterpret_cast<f32x4*>(Cf + (size_t)dst * 8192 + m0) = pk;
          if (!diag)  // strict-upper (r,c) <-> strict-lower (c,r) bijection
            *reinterpret_cast<f32x4*>(Cf + (size_t)mir * 8192 + m0) = z;
        }
      }
    }
  }
}

// ---------------------------------------------------------------------------
// Weight transpose + fp32->bf16: in[K,N](f32) -> out[NP,K](bf16), rows >= N zero
// ---------------------------------------------------------------------------
__global__ void transpose_k(const float* __restrict__ in,
                            __hip_bfloat16* __restrict__ out,
                            int K, int N)
{
  __shared__ __hip_bfloat16 t[32][33];
  const int n0 = blockIdx.x * 32;
  const int k0 = blockIdx.y * 32;
  const int tx = threadIdx.x, ty = threadIdx.y;
  const __hip_bfloat16 zero = __float2bfloat16(0.f);
#pragma unroll
  for (int r = 0; r < 32; r += 8) {
    int k = k0 + ty + r, n = n0 + tx;
    t[ty + r][tx] = (n < N) ? __float2bfloat16(in[(size_t)k * N + n]) : zero;
  }
  __syncthreads();
#pragma unroll
  for (int r = 0; r < 32; r += 8) {
    int n = n0 + ty + r;
    out[(size_t)n * K + k0 + tx] = t[tx][ty + r];
  }
}

// fp32 -> bf16 elementwise (x), 4 per thread
__global__ void cvt_k(const float* __restrict__ in,
                      __hip_bfloat16* __restrict__ out, int n)
{
  int i = (blockIdx.x * 256 + threadIdx.x) * 4;
  if (i >= n) return;
  float4 v = *reinterpret_cast<const float4*>(in + i);
  union { unsigned short us[4]; uint2 v2; } pk;
  __hip_bfloat16 h;
  h = __float2bfloat16(v.x); pk.us[0] = *reinterpret_cast<unsigned short*>(&h);
  h = __float2bfloat16(v.y); pk.us[1] = *reinterpret_cast<unsigned short*>(&h);
  h = __float2bfloat16(v.z); pk.us[2] = *reinterpret_cast<unsigned short*>(&h);
  h = __float2bfloat16(v.w); pk.us[3] = *reinterpret_cast<unsigned short*>(&h);
  *reinterpret_cast<uint2*>(out + i) = pk.v2;
}

// l -> (r,c) scatter table. Row r covers cols 63..r; diag (c==r) flagged bit 12.
__global__ void table_k(int* __restrict__ tbl)
{
  int l = blockIdx.x * 64 + threadIdx.x;
  if (l >= 2080) return;
  int r = 0, s = 0;
  while (s + (64 - r) <= l) { s += 64 - r; ++r; }
  int c = 63 - (l - s);
  tbl[l] = (r * 64 + c) | ((r == c) ? 4096 : 0);
}

extern "C" void kernel_launch(void* const* d_in, const int* in_sizes, int n_in,
                              void* d_out, int out_size, void* d_ws, size_t ws_size,
                              hipStream_t stream)
{
  const float* x   = (const float*)d_in[0];
  const float* W1  = (const float*)d_in[1];
  const float* b1  = (const float*)d_in[2];
  const float* W2  = (const float*)d_in[3];
  const float* b2  = (const float*)d_in[4];
  const float* W21 = (const float*)d_in[5];
  const float* b21 = (const float*)d_in[6];
  const float* W22 = (const float*)d_in[7];
  const float* b22 = (const float*)d_in[8];
  const float* W3  = (const float*)d_in[9];
  const float* b3  = (const float*)d_in[10];
  float* out = (float*)d_out;

  char* ws = (char*)d_ws;
  __hip_bfloat16* act0 = (__hip_bfloat16*)(ws);                         // 8192x2048 bf16
  __hip_bfloat16* act1 = (__hip_bfloat16*)(ws + ((size_t)32 << 20));    // 8192x2048 bf16
  __hip_bfloat16* xb   = act1;                                          // 8192x1024 bf16 (dead after GEMM1)
  __hip_bfloat16* W1T  = (__hip_bfloat16*)(ws + ((size_t)64 << 20));    // 2048x1024
  __hip_bfloat16* W2T  = (__hip_bfloat16*)(ws + ((size_t)68 << 20));    // 2048x2048
  __hip_bfloat16* W21T = (__hip_bfloat16*)(ws + ((size_t)76 << 20));    // 2048x2048
  __hip_bfloat16* W22T = (__hip_bfloat16*)(ws + ((size_t)84 << 20));    // 2048x2048
  __hip_bfloat16* W3T  = (__hip_bfloat16*)(ws + ((size_t)92 << 20));    // 2176x2048 (zero-padded)
  int*            tbl  = (int*)(ws + ((size_t)101 << 20));              // 2080 ints

  // No output memset: FINAL gemm writes upper triangle + mirrored zeros.
  table_k<<<33, 64, 0, stream>>>(tbl);

  cvt_k<<<8192, 256, 0, stream>>>(x, xb, 8192 * 1024);

  dim3 tb(32, 8);
  transpose_k<<<dim3(64, 32), tb, 0, stream>>>(W1,  W1T,  1024, 2048);
  transpose_k<<<dim3(64, 64), tb, 0, stream>>>(W2,  W2T,  2048, 2048);
  transpose_k<<<dim3(64, 64), tb, 0, stream>>>(W21, W21T, 2048, 2048);
  transpose_k<<<dim3(64, 64), tb, 0, stream>>>(W22, W22T, 2048, 2048);
  transpose_k<<<dim3(68, 64), tb, 0, stream>>>(W3,  W3T,  2048, 2080); // rows 2080..2175 zero

  gemm_k<0><<<dim3(64, 16), 256, 0, stream>>>(xb,   W1T,  b1,  act0, nullptr, nullptr, 1024, 2048);
  gemm_k<0><<<dim3(64, 16), 256, 0, stream>>>(act0, W2T,  b2,  act1, nullptr, nullptr, 2048, 2048);
  gemm_k<0><<<dim3(64, 16), 256, 0, stream>>>(act1, W21T, b21, act0, nullptr, nullptr, 2048, 2048);
  gemm_k<0><<<dim3(64, 16), 256, 0, stream>>>(act0, W22T, b22, act1, nullptr, nullptr, 2048, 2048);
  gemm_k<1><<<dim3(64, 17), 256, 0, stream>>>(act1, W3T,  b3,  nullptr, out,  tbl,     2048, 2080);
}

// Round 9
// 570.597 us; speedup vs baseline: 1.0893x; 1.0893x over previous
//
#include <hip/hip_runtime.h>
#include <hip/hip_bf16.h>
#include <stdint.h>

typedef short short8 __attribute__((ext_vector_type(8)));
typedef float f32x4  __attribute__((ext_vector_type(4)));

typedef __attribute__((address_space(1))) uint32_t u32_g;
typedef __attribute__((address_space(3))) uint32_t u32_l;

#define BM 128
#define BN 128
#define BK 64

// async global->LDS, 16 bytes per lane. LDS dest must be wave-uniform base +
// lane*16 contiguous (generic LDS pointer low 32 bits == LDS offset on amdgcn).
__device__ __forceinline__ void gld_lds16(const void* g, const void* l) {
  __builtin_amdgcn_global_load_lds((u32_g*)(uintptr_t)g, (u32_l*)(uintptr_t)l, 16, 0, 0);
}

// ---------------------------------------------------------------------------
// GEMM: C = epilogue(A[M,K](bf16) @ BT[N,K](bf16)^T + bias(fp32))
// r7 structure (measured best, 561.5us total): classic LDS double-buffer,
// ONE __syncthreads per K-step; stage(k+1) issued BEFORE compute(k) so the
// sync's vmcnt(0) drain targets a DMA with a full K-step (~2000cyc) of cover.
// Five controlled schedule experiments (r0/r2/r3/r4/r8) all lose to this:
// barrier-period overhead per 32 MFMAs at 2 blocks/CU is the sweet spot.
// FINAL=0: leaky-relu, bf16 -> Cb (stride 2048), j-inner store order
//          (full 128B lines close within 4 consecutive stores).
// FINAL=1: diag-abs + triangle scatter fp32 Cf[(r*64+c)*8192+m], plus
//          zero-store to mirrored lower-triangle slot (replaces memset).
// ---------------------------------------------------------------------------
template <int FINAL>
__global__ __launch_bounds__(256) void gemm_k(
    const __hip_bfloat16* __restrict__ A,
    const __hip_bfloat16* __restrict__ BT,
    const float* __restrict__ bias,
    __hip_bfloat16* __restrict__ Cb,
    float* __restrict__ Cf,
    const int* __restrict__ tbl,
    int K, int Nreal)
{
  // dbuf arena: buf b at b*32768; A at +0 (16K), B at +16384 (16K).
  __shared__ __attribute__((aligned(16))) char smem[65536];

  const int tid  = threadIdx.x;
  const int lane = tid & 63;
  const int l15  = lane & 15;
  const int quad = lane >> 4;
  const int wave = tid >> 6;
  const int wm   = (wave >> 1) << 6;   // wave row offset within 128-tile
  const int wn   = (wave & 1) << 6;    // wave col offset

  const int bm = blockIdx.x * BM;
  const int bn = blockIdx.y * BN;

  // Staging: tile rows are 64 bf16 = 8 chunks of 16B. chunk ci = tid + 256*c.
  // XOR-swizzle the chunk on the GLOBAL side so LDS stays wave-contiguous
  // (global_load_lds constraint) while fragment reads (128B stride) spread
  // across banks.
  const __hip_bfloat16* ag[4];
  const __hip_bfloat16* bg[4];
  uint32_t lofs[4];
#pragma unroll
  for (int c = 0; c < 4; ++c) {
    int ci   = tid + 256 * c;        // 0..1023
    int row  = ci >> 3;              // 0..127
    int chk  = ci & 7;
    int gchk = chk ^ (row & 7);
    ag[c]   = A  + (size_t)(bm + row) * K + gchk * 8;
    bg[c]   = BT + (size_t)(bn + row) * K + gchk * 8;
    lofs[c] = (uint32_t)ci * 16u;
  }

  f32x4 acc[4][4];
#pragma unroll
  for (int i = 0; i < 4; ++i)
#pragma unroll
    for (int j = 0; j < 4; ++j)
      acc[i][j] = (f32x4){0.f, 0.f, 0.f, 0.f};

  const int nk = K >> 6;

  // prologue: stage tile 0 into buf0, drain at the sync
#pragma unroll
  for (int c = 0; c < 4; ++c) {
    gld_lds16(ag[c], smem + lofs[c]);
    gld_lds16(bg[c], smem + 16384 + lofs[c]);
    ag[c] += BK;
    bg[c] += BK;
  }
  __syncthreads();

  for (int kt = 0; kt < nk; ++kt) {
    const char* rb = smem + (kt & 1) * 32768;
    char*       sb = smem + ((kt + 1) & 1) * 32768;

    // issue next tile's staging FIRST -- latency hides under this step's MFMA
    if (kt + 1 < nk) {
#pragma unroll
      for (int c = 0; c < 4; ++c) {
        gld_lds16(ag[c], sb + lofs[c]);
        gld_lds16(bg[c], sb + 16384 + lofs[c]);
        ag[c] += BK;
        bg[c] += BK;
      }
    }

#pragma unroll
    for (int ks = 0; ks < 2; ++ks) {
      short8 af[4], bf[4];
      const int cf = ks * 4 + quad;  // 8-elem k-chunk of the 64-wide row
#pragma unroll
      for (int i = 0; i < 4; ++i) {
        int m  = wm + i * 16 + l15;
        int sc = cf ^ (m & 7);
        af[i]  = *(const short8*)(rb + m * 128 + sc * 16);
      }
#pragma unroll
      for (int j = 0; j < 4; ++j) {
        int n  = wn + j * 16 + l15;
        int sc = cf ^ (n & 7);
        bf[j]  = *(const short8*)(rb + 16384 + n * 128 + sc * 16);
      }
#pragma unroll
      for (int i = 0; i < 4; ++i)
#pragma unroll
        for (int j = 0; j < 4; ++j)
          acc[i][j] = __builtin_amdgcn_mfma_f32_16x16x32_bf16(af[i], bf[j], acc[i][j], 0, 0, 0);
    }
    // single barrier: (a) vmcnt(0) drain of stage(kt+1) -- issued ~2000cyc
    // ago, hidden; (b) all waves done reading rb before it's restaged next step.
    __syncthreads();
  }

  // Epilogue. C/D layout: col = lane&15, row = quad*4 + reg (m89-verified).
  if (FINAL == 0) {
    float bv[4];
#pragma unroll
    for (int j = 0; j < 4; ++j) bv[j] = bias[bn + wn + j * 16 + l15];
#pragma unroll
    for (int i = 0; i < 4; ++i) {
#pragma unroll
      for (int r = 0; r < 4; ++r) {
        const size_t rowoff = (size_t)(bm + wm + i * 16 + quad * 4 + r) * 2048;
#pragma unroll
        for (int j = 0; j < 4; ++j) {   // 4 consecutive 32B bursts -> full 128B line
          int n = bn + wn + j * 16 + l15;
          float v = acc[i][j][r] + bv[j];
          v = (v > 0.f) ? v : 0.01f * v;
          Cb[rowoff + n] = __float2bfloat16(v);
        }
      }
    }
  } else {
#pragma unroll
    for (int j = 0; j < 4; ++j) {
      int n = bn + wn + j * 16 + l15;
      if (n < Nreal) {
        float bv   = bias[n];
        int  code  = tbl[n];
        int  dst   = code & 4095;          // r*64 + c (upper triangle)
        bool diag  = (code & 4096) != 0;
        int  mir   = ((dst & 63) << 6) | (dst >> 6);  // (c,r) lower mirror
        const f32x4 z = (f32x4){0.f, 0.f, 0.f, 0.f};
#pragma unroll
        for (int i = 0; i < 4; ++i) {
          int m0 = bm + wm + i * 16 + quad * 4;
          f32x4 pk;
#pragma unroll
          for (int r = 0; r < 4; ++r) {
            float v = acc[i][j][r] + bv;
            if (diag) v = fabsf(v);
            pk[r] = v;
          }
          // 4 consecutive batch rows at one (r,c): aligned 16B store
          *reinterpret_cast<f32x4*>(Cf + (size_t)dst * 8192 + m0) = pk;
          if (!diag)  // strict-upper (r,c) <-> strict-lower (c,r) bijection
            *reinterpret_cast<f32x4*>(Cf + (size_t)mir * 8192 + m0) = z;
        }
      }
    }
  }
}

// ---------------------------------------------------------------------------
// Weight transpose + fp32->bf16: in[K,N](f32) -> out[NP,K](bf16), rows >= N zero
// ---------------------------------------------------------------------------
__global__ void transpose_k(const float* __restrict__ in,
                            __hip_bfloat16* __restrict__ out,
                            int K, int N)
{
  __shared__ __hip_bfloat16 t[32][33];
  const int n0 = blockIdx.x * 32;
  const int k0 = blockIdx.y * 32;
  const int tx = threadIdx.x, ty = threadIdx.y;
  const __hip_bfloat16 zero = __float2bfloat16(0.f);
#pragma unroll
  for (int r = 0; r < 32; r += 8) {
    int k = k0 + ty + r, n = n0 + tx;
    t[ty + r][tx] = (n < N) ? __float2bfloat16(in[(size_t)k * N + n]) : zero;
  }
  __syncthreads();
#pragma unroll
  for (int r = 0; r < 32; r += 8) {
    int n = n0 + ty + r;
    out[(size_t)n * K + k0 + tx] = t[tx][ty + r];
  }
}

// batched square-transpose for the three 2048x2048 weights (one launch)
__global__ void transpose3_k(const float* __restrict__ in0,
                             const float* __restrict__ in1,
                             const float* __restrict__ in2,
                             __hip_bfloat16* __restrict__ out0,
                             __hip_bfloat16* __restrict__ out1,
                             __hip_bfloat16* __restrict__ out2)
{
  const float* in  = (blockIdx.z == 0) ? in0  : (blockIdx.z == 1) ? in1  : in2;
  __hip_bfloat16* out = (blockIdx.z == 0) ? out0 : (blockIdx.z == 1) ? out1 : out2;
  __shared__ __hip_bfloat16 t[32][33];
  const int n0 = blockIdx.x * 32;
  const int k0 = blockIdx.y * 32;
  const int tx = threadIdx.x, ty = threadIdx.y;
#pragma unroll
  for (int r = 0; r < 32; r += 8) {
    int k = k0 + ty + r, n = n0 + tx;
    t[ty + r][tx] = __float2bfloat16(in[(size_t)k * 2048 + n]);
  }
  __syncthreads();
#pragma unroll
  for (int r = 0; r < 32; r += 8) {
    int n = n0 + ty + r;
    out[(size_t)n * 2048 + k0 + tx] = t[tx][ty + r];
  }
}

// fp32 -> bf16 elementwise (x), 8 per thread (2x float4 in, one 16B store out)
__global__ void cvt_k(const float* __restrict__ in,
                      __hip_bfloat16* __restrict__ out, int n)
{
  int i = (blockIdx.x * 256 + threadIdx.x) * 8;
  if (i >= n) return;
  float4 v0 = *reinterpret_cast<const float4*>(in + i);
  float4 v1 = *reinterpret_cast<const float4*>(in + i + 4);
  union { unsigned short us[8]; uint4 v4; } pk;
  __hip_bfloat16 h;
  h = __float2bfloat16(v0.x); pk.us[0] = *reinterpret_cast<unsigned short*>(&h);
  h = __float2bfloat16(v0.y); pk.us[1] = *reinterpret_cast<unsigned short*>(&h);
  h = __float2bfloat16(v0.z); pk.us[2] = *reinterpret_cast<unsigned short*>(&h);
  h = __float2bfloat16(v0.w); pk.us[3] = *reinterpret_cast<unsigned short*>(&h);
  h = __float2bfloat16(v1.x); pk.us[4] = *reinterpret_cast<unsigned short*>(&h);
  h = __float2bfloat16(v1.y); pk.us[5] = *reinterpret_cast<unsigned short*>(&h);
  h = __float2bfloat16(v1.z); pk.us[6] = *reinterpret_cast<unsigned short*>(&h);
  h = __float2bfloat16(v1.w); pk.us[7] = *reinterpret_cast<unsigned short*>(&h);
  *reinterpret_cast<uint4*>(out + i) = pk.v4;
}

// l -> (r,c) scatter table. Row r covers cols 63..r; diag (c==r) flagged bit 12.
__global__ void table_k(int* __restrict__ tbl)
{
  int l = blockIdx.x * 64 + threadIdx.x;
  if (l >= 2080) return;
  int r = 0, s = 0;
  while (s + (64 - r) <= l) { s += 64 - r; ++r; }
  int c = 63 - (l - s);
  tbl[l] = (r * 64 + c) | ((r == c) ? 4096 : 0);
}

extern "C" void kernel_launch(void* const* d_in, const int* in_sizes, int n_in,
                              void* d_out, int out_size, void* d_ws, size_t ws_size,
                              hipStream_t stream)
{
  const float* x   = (const float*)d_in[0];
  const float* W1  = (const float*)d_in[1];
  const float* b1  = (const float*)d_in[2];
  const float* W2  = (const float*)d_in[3];
  const float* b2  = (const float*)d_in[4];
  const float* W21 = (const float*)d_in[5];
  const float* b21 = (const float*)d_in[6];
  const float* W22 = (const float*)d_in[7];
  const float* b22 = (const float*)d_in[8];
  const float* W3  = (const float*)d_in[9];
  const float* b3  = (const float*)d_in[10];
  float* out = (float*)d_out;

  char* ws = (char*)d_ws;
  __hip_bfloat16* act0 = (__hip_bfloat16*)(ws);                         // 8192x2048 bf16
  __hip_bfloat16* act1 = (__hip_bfloat16*)(ws + ((size_t)32 << 20));    // 8192x2048 bf16
  __hip_bfloat16* xb   = act1;                                          // 8192x1024 bf16 (dead after GEMM1)
  __hip_bfloat16* W1T  = (__hip_bfloat16*)(ws + ((size_t)64 << 20));    // 2048x1024
  __hip_bfloat16* W2T  = (__hip_bfloat16*)(ws + ((size_t)68 << 20));    // 2048x2048
  __hip_bfloat16* W21T = (__hip_bfloat16*)(ws + ((size_t)76 << 20));    // 2048x2048
  __hip_bfloat16* W22T = (__hip_bfloat16*)(ws + ((size_t)84 << 20));    // 2048x2048
  __hip_bfloat16* W3T  = (__hip_bfloat16*)(ws + ((size_t)92 << 20));    // 2176x2048 (zero-padded)
  int*            tbl  = (int*)(ws + ((size_t)101 << 20));              // 2080 ints

  // No output memset: FINAL gemm writes upper triangle + mirrored zeros.
  table_k<<<33, 64, 0, stream>>>(tbl);

  cvt_k<<<4096, 256, 0, stream>>>(x, xb, 8192 * 1024);

  dim3 tb(32, 8);
  transpose_k<<<dim3(64, 32), tb, 0, stream>>>(W1, W1T, 1024, 2048);
  transpose3_k<<<dim3(64, 64, 3), tb, 0, stream>>>(W2, W21, W22, W2T, W21T, W22T);
  transpose_k<<<dim3(68, 64), tb, 0, stream>>>(W3, W3T, 2048, 2080); // rows 2080..2175 zero

  gemm_k<0><<<dim3(64, 16), 256, 0, stream>>>(xb,   W1T,  b1,  act0, nullptr, nullptr, 1024, 2048);
  gemm_k<0><<<dim3(64, 16), 256, 0, stream>>>(act0, W2T,  b2,  act1, nullptr, nullptr, 2048, 2048);
  gemm_k<0><<<dim3(64, 16), 256, 0, stream>>>(act1, W21T, b21, act0, nullptr, nullptr, 2048, 2048);
  gemm_k<0><<<dim3(64, 16), 256, 0, stream>>>(act0, W22T, b22, act1, nullptr, nullptr, 2048, 2048);
  gemm_k<1><<<dim3(64, 17), 256, 0, stream>>>(act1, W3T,  b3,  nullptr, out,  tbl,     2048, 2080);
}

// Round 10
// 569.506 us; speedup vs baseline: 1.0914x; 1.0019x over previous
//
#include <hip/hip_runtime.h>
#include <hip/hip_bf16.h>
#include <stdint.h>

typedef short short8 __attribute__((ext_vector_type(8)));
typedef float f32x4  __attribute__((ext_vector_type(4)));

typedef __attribute__((address_space(1))) uint32_t u32_g;
typedef __attribute__((address_space(3))) uint32_t u32_l;

#define BM 128
#define BN 128
#define BK 64

// async global->LDS, 16 bytes per lane. LDS dest must be wave-uniform base +
// lane*16 contiguous (generic LDS pointer low 32 bits == LDS offset on amdgcn).
__device__ __forceinline__ void gld_lds16(const void* g, const void* l) {
  __builtin_amdgcn_global_load_lds((u32_g*)(uintptr_t)g, (u32_l*)(uintptr_t)l, 16, 0, 0);
}

// ---------------------------------------------------------------------------
// GEMM: C = epilogue(A[M,K](bf16) @ BT[N,K](bf16)^T + bias(fp32))
// r7 schedule (measured best): LDS double-buffer, ONE __syncthreads per
// K-step, stage(k+1) issued before compute(k). This round: 512-thread blocks
// (8 waves, wave tile 64x32) on the same 128^2 tile / 64KiB LDS -> still
// 2 blocks/CU but 4 waves/SIMD (2 per block), so during one block's barrier
// drain each SIMD has 2 runnable waves from the other block instead of 1.
// FINAL=0: leaky-relu, bf16 -> Cb (stride 2048), j-inner store order.
// FINAL=1: diag-abs + triangle scatter fp32 Cf[(r*64+c)*8192+m], plus
//          zero-store to mirrored lower-triangle slot (replaces memset).
// ---------------------------------------------------------------------------
template <int FINAL>
__global__ __launch_bounds__(512) void gemm_k(
    const __hip_bfloat16* __restrict__ A,
    const __hip_bfloat16* __restrict__ BT,
    const float* __restrict__ bias,
    __hip_bfloat16* __restrict__ Cb,
    float* __restrict__ Cf,
    const int* __restrict__ tbl,
    int K, int Nreal)
{
  // dbuf arena: buf b at b*32768; A at +0 (16K), B at +16384 (16K).
  __shared__ __attribute__((aligned(16))) char smem[65536];

  const int tid  = threadIdx.x;
  const int lane = tid & 63;
  const int l15  = lane & 15;
  const int quad = lane >> 4;
  const int wave = tid >> 6;           // 0..7
  const int wm   = (wave >> 2) * 64;   // 2 wave-rows in M
  const int wn   = (wave & 3) * 32;    // 4 wave-cols in N

  const int bm = blockIdx.x * BM;
  const int bn = blockIdx.y * BN;

  // Staging: tile rows are 64 bf16 = 8 chunks of 16B. chunk ci = tid + 512*c.
  // XOR-swizzle the chunk on the GLOBAL side so LDS stays wave-contiguous
  // (global_load_lds constraint) while fragment reads (128B stride) spread
  // across banks.
  const __hip_bfloat16* ag[2];
  const __hip_bfloat16* bg[2];
  uint32_t lofs[2];
#pragma unroll
  for (int c = 0; c < 2; ++c) {
    int ci   = tid + 512 * c;        // 0..1023
    int row  = ci >> 3;              // 0..127
    int chk  = ci & 7;
    int gchk = chk ^ (row & 7);
    ag[c]   = A  + (size_t)(bm + row) * K + gchk * 8;
    bg[c]   = BT + (size_t)(bn + row) * K + gchk * 8;
    lofs[c] = (uint32_t)ci * 16u;
  }

  f32x4 acc[4][2];
#pragma unroll
  for (int i = 0; i < 4; ++i)
#pragma unroll
    for (int j = 0; j < 2; ++j)
      acc[i][j] = (f32x4){0.f, 0.f, 0.f, 0.f};

  const int nk = K >> 6;

  // prologue: stage tile 0 into buf0, drain at the sync
#pragma unroll
  for (int c = 0; c < 2; ++c) {
    gld_lds16(ag[c], smem + lofs[c]);
    gld_lds16(bg[c], smem + 16384 + lofs[c]);
    ag[c] += BK;
    bg[c] += BK;
  }
  __syncthreads();

  for (int kt = 0; kt < nk; ++kt) {
    const char* rb = smem + (kt & 1) * 32768;
    char*       sb = smem + ((kt + 1) & 1) * 32768;

    // issue next tile's staging FIRST -- latency hides under this step's MFMA
    if (kt + 1 < nk) {
#pragma unroll
      for (int c = 0; c < 2; ++c) {
        gld_lds16(ag[c], sb + lofs[c]);
        gld_lds16(bg[c], sb + 16384 + lofs[c]);
        ag[c] += BK;
        bg[c] += BK;
      }
    }

#pragma unroll
    for (int ks = 0; ks < 2; ++ks) {
      short8 af[4], bf[2];
      const int cf = ks * 4 + quad;  // 8-elem k-chunk of the 64-wide row
#pragma unroll
      for (int i = 0; i < 4; ++i) {
        int m  = wm + i * 16 + l15;
        int sc = cf ^ (m & 7);
        af[i]  = *(const short8*)(rb + m * 128 + sc * 16);
      }
#pragma unroll
      for (int j = 0; j < 2; ++j) {
        int n  = wn + j * 16 + l15;
        int sc = cf ^ (n & 7);
        bf[j]  = *(const short8*)(rb + 16384 + n * 128 + sc * 16);
      }
#pragma unroll
      for (int i = 0; i < 4; ++i)
#pragma unroll
        for (int j = 0; j < 2; ++j)
          acc[i][j] = __builtin_amdgcn_mfma_f32_16x16x32_bf16(af[i], bf[j], acc[i][j], 0, 0, 0);
    }
    // single barrier: (a) vmcnt(0) drain of stage(kt+1) -- issued one full
    // K-step ago; (b) all waves done reading rb before it's restaged.
    __syncthreads();
  }

  // Epilogue. C/D layout: col = lane&15, row = quad*4 + reg (m89-verified).
  if (FINAL == 0) {
    float bv[2];
#pragma unroll
    for (int j = 0; j < 2; ++j) bv[j] = bias[bn + wn + j * 16 + l15];
#pragma unroll
    for (int i = 0; i < 4; ++i) {
#pragma unroll
      for (int r = 0; r < 4; ++r) {
        const size_t rowoff = (size_t)(bm + wm + i * 16 + quad * 4 + r) * 2048;
#pragma unroll
        for (int j = 0; j < 2; ++j) {
          int n = bn + wn + j * 16 + l15;
          float v = acc[i][j][r] + bv[j];
          v = (v > 0.f) ? v : 0.01f * v;
          Cb[rowoff + n] = __float2bfloat16(v);
        }
      }
    }
  } else {
#pragma unroll
    for (int j = 0; j < 2; ++j) {
      int n = bn + wn + j * 16 + l15;
      if (n < Nreal) {
        float bv   = bias[n];
        int  code  = tbl[n];
        int  dst   = code & 4095;          // r*64 + c (upper triangle)
        bool diag  = (code & 4096) != 0;
        int  mir   = ((dst & 63) << 6) | (dst >> 6);  // (c,r) lower mirror
        const f32x4 z = (f32x4){0.f, 0.f, 0.f, 0.f};
#pragma unroll
        for (int i = 0; i < 4; ++i) {
          int m0 = bm + wm + i * 16 + quad * 4;
          f32x4 pk;
#pragma unroll
          for (int r = 0; r < 4; ++r) {
            float v = acc[i][j][r] + bv;
            if (diag) v = fabsf(v);
            pk[r] = v;
          }
          // 4 consecutive batch rows at one (r,c): aligned 16B store
          *reinterpret_cast<f32x4*>(Cf + (size_t)dst * 8192 + m0) = pk;
          if (!diag)  // strict-upper (r,c) <-> strict-lower (c,r) bijection
            *reinterpret_cast<f32x4*>(Cf + (size_t)mir * 8192 + m0) = z;
        }
      }
    }
  }
}

// ---------------------------------------------------------------------------
// Weight transpose + fp32->bf16: in[K,N](f32) -> out[NP,K](bf16), rows >= N zero
// ---------------------------------------------------------------------------
__global__ void transpose_k(const float* __restrict__ in,
                            __hip_bfloat16* __restrict__ out,
                            int K, int N)
{
  __shared__ __hip_bfloat16 t[32][33];
  const int n0 = blockIdx.x * 32;
  const int k0 = blockIdx.y * 32;
  const int tx = threadIdx.x, ty = threadIdx.y;
  const __hip_bfloat16 zero = __float2bfloat16(0.f);
#pragma unroll
  for (int r = 0; r < 32; r += 8) {
    int k = k0 + ty + r, n = n0 + tx;
    t[ty + r][tx] = (n < N) ? __float2bfloat16(in[(size_t)k * N + n]) : zero;
  }
  __syncthreads();
#pragma unroll
  for (int r = 0; r < 32; r += 8) {
    int n = n0 + ty + r;
    out[(size_t)n * K + k0 + tx] = t[tx][ty + r];
  }
}

// fp32 -> bf16 elementwise (x), 4 per thread
__global__ void cvt_k(const float* __restrict__ in,
                      __hip_bfloat16* __restrict__ out, int n)
{
  int i = (blockIdx.x * 256 + threadIdx.x) * 4;
  if (i >= n) return;
  float4 v = *reinterpret_cast<const float4*>(in + i);
  union { unsigned short us[4]; uint2 v2; } pk;
  __hip_bfloat16 h;
  h = __float2bfloat16(v.x); pk.us[0] = *reinterpret_cast<unsigned short*>(&h);
  h = __float2bfloat16(v.y); pk.us[1] = *reinterpret_cast<unsigned short*>(&h);
  h = __float2bfloat16(v.z); pk.us[2] = *reinterpret_cast<unsigned short*>(&h);
  h = __float2bfloat16(v.w); pk.us[3] = *reinterpret_cast<unsigned short*>(&h);
  *reinterpret_cast<uint2*>(out + i) = pk.v2;
}

// l -> (r,c) scatter table. Row r covers cols 63..r; diag (c==r) flagged bit 12.
__global__ void table_k(int* __restrict__ tbl)
{
  int l = blockIdx.x * 64 + threadIdx.x;
  if (l >= 2080) return;
  int r = 0, s = 0;
  while (s + (64 - r) <= l) { s += 64 - r; ++r; }
  int c = 63 - (l - s);
  tbl[l] = (r * 64 + c) | ((r == c) ? 4096 : 0);
}

extern "C" void kernel_launch(void* const* d_in, const int* in_sizes, int n_in,
                              void* d_out, int out_size, void* d_ws, size_t ws_size,
                              hipStream_t stream)
{
  const float* x   = (const float*)d_in[0];
  const float* W1  = (const float*)d_in[1];
  const float* b1  = (const float*)d_in[2];
  const float* W2  = (const float*)d_in[3];
  const float* b2  = (const float*)d_in[4];
  const float* W21 = (const float*)d_in[5];
  const float* b21 = (const float*)d_in[6];
  const float* W22 = (const float*)d_in[7];
  const float* b22 = (const float*)d_in[8];
  const float* W3  = (const float*)d_in[9];
  const float* b3  = (const float*)d_in[10];
  float* out = (float*)d_out;

  char* ws = (char*)d_ws;
  __hip_bfloat16* act0 = (__hip_bfloat16*)(ws);                         // 8192x2048 bf16
  __hip_bfloat16* act1 = (__hip_bfloat16*)(ws + ((size_t)32 << 20));    // 8192x2048 bf16
  __hip_bfloat16* xb   = act1;                                          // 8192x1024 bf16 (dead after GEMM1)
  __hip_bfloat16* W1T  = (__hip_bfloat16*)(ws + ((size_t)64 << 20));    // 2048x1024
  __hip_bfloat16* W2T  = (__hip_bfloat16*)(ws + ((size_t)68 << 20));    // 2048x2048
  __hip_bfloat16* W21T = (__hip_bfloat16*)(ws + ((size_t)76 << 20));    // 2048x2048
  __hip_bfloat16* W22T = (__hip_bfloat16*)(ws + ((size_t)84 << 20));    // 2048x2048
  __hip_bfloat16* W3T  = (__hip_bfloat16*)(ws + ((size_t)92 << 20));    // 2176x2048 (zero-padded)
  int*            tbl  = (int*)(ws + ((size_t)101 << 20));              // 2080 ints

  // No output memset: FINAL gemm writes upper triangle + mirrored zeros.
  table_k<<<33, 64, 0, stream>>>(tbl);

  cvt_k<<<8192, 256, 0, stream>>>(x, xb, 8192 * 1024);

  dim3 tb(32, 8);
  transpose_k<<<dim3(64, 32), tb, 0, stream>>>(W1,  W1T,  1024, 2048);
  transpose_k<<<dim3(64, 64), tb, 0, stream>>>(W2,  W2T,  2048, 2048);
  transpose_k<<<dim3(64, 64), tb, 0, stream>>>(W21, W21T, 2048, 2048);
  transpose_k<<<dim3(64, 64), tb, 0, stream>>>(W22, W22T, 2048, 2048);
  transpose_k<<<dim3(68, 64), tb, 0, stream>>>(W3,  W3T,  2048, 2080); // rows 2080..2175 zero

  gemm_k<0><<<dim3(64, 16), 512, 0, stream>>>(xb,   W1T,  b1,  act0, nullptr, nullptr, 1024, 2048);
  gemm_k<0><<<dim3(64, 16), 512, 0, stream>>>(act0, W2T,  b2,  act1, nullptr, nullptr, 2048, 2048);
  gemm_k<0><<<dim3(64, 16), 512, 0, stream>>>(act1, W21T, b21, act0, nullptr, nullptr, 2048, 2048);
  gemm_k<0><<<dim3(64, 16), 512, 0, stream>>>(act0, W22T, b22, act1, nullptr, nullptr, 2048, 2048);
  gemm_k<1><<<dim3(64, 17), 512, 0, stream>>>(act1, W3T,  b3,  nullptr, out,  tbl,     2048, 2080);
}